// Round 8
// baseline (148.031 us; speedup 1.0000x reference)
//
#include <hip/hip_runtime.h>
#include <stdint.h>
#include <stddef.h>

#define Tdim 4096
#define Hdim 2048

typedef short short8 __attribute__((ext_vector_type(8)));
typedef float floatx4 __attribute__((ext_vector_type(4)));
typedef float f32x4 __attribute__((ext_vector_type(4)));  // builtin vec: AS1-deref OK

// RNE fp32 -> bf16 bit pattern
__device__ __forceinline__ unsigned short f2bf(float f) {
  uint32_t u = __float_as_uint(f);
  u += 0x7fffu + ((u >> 16) & 1u);
  return (unsigned short)(u >> 16);
}

// async global->LDS, 16B per lane. LDS dest is wave-uniform base + lane*16.
__device__ __forceinline__ void load_lds16(const void* g, void* l) {
  __builtin_amdgcn_global_load_lds(
      (__attribute__((address_space(1))) unsigned int*)(uintptr_t)g,
      (__attribute__((address_space(3))) unsigned int*)l,
      16, 0, 0);
}

__device__ __forceinline__ float tanh_fast(float z) {
  // tanh(z) = 1 - 2/(exp(2z)+1); safe for all z
  float e = __expf(z + z);
  return 1.0f - __fdividef(2.0f, e + 1.0f);
}

// aligned LDS vector read (forces ds_read_b128)
__device__ __forceinline__ short8 lds_read8(const unsigned short* p) {
  return *(const short8*)__builtin_assume_aligned(p, 16);
}

// address_space(1)-forced fp32 vector load: guarantees global_load_dwordx4
// (vmcnt-only; a generic-pointer load may emit flat_load which also bumps
// lgkmcnt and chains ds_read waits to it -- the r14 failure mechanism).
// NOTE: must use the builtin ext_vector type, NOT HIP float4 -- the
// HIP_vector_type copy-ctor cannot bind an AS1 reference (r18 compile fail).
typedef __attribute__((address_space(1))) const f32x4* gptrf4;
__device__ __forceinline__ f32x4 glb_readf4(const float* p) {
  return *(gptrf4)(uintptr_t)__builtin_assume_aligned(p, 16);
}

// Explicit barrier-with-drain. r16 (8-wave variant, no explicit drain)
// raced: outputs diverged after graph replays (absmax 0.87 = one stale
// LDS tile). The compiler's vmcnt(0)-before-s_barrier is observed codegen
// (m97), not a guarantee. Make the contract explicit: drain vmcnt (B glds
// DMA, A fp32 loads) + lgkmcnt (A ds_writes), then barrier.
#define SYNC_DRAIN()                                                   \
  do {                                                                 \
    asm volatile("s_waitcnt vmcnt(0) lgkmcnt(0)" ::: "memory");        \
    __syncthreads();                                                   \
  } while (0)

// ---- cvt: transpose+cast b (HxH fp32, [k][n]) -> bt bf16 (N x K, [n][k]).
// The x -> bf16 cast pass (4096 blocks, 48.8 MB of HBM round trip) is
// GONE -- the GEMM converts x inline during A-staging.
__global__ __launch_bounds__(256) void cvt_kernel(const float* __restrict__ b,
                                                  unsigned short* __restrict__ bt) {
  __shared__ unsigned short tile[64 * 65];
  const int t = threadIdx.x;
  const int tb = blockIdx.x;
  const int bj = tb & 31;  // n block
  const int bi = tb >> 5;  // k block
  {
    const int r0 = t >> 4, c4 = (t & 15) * 4;
#pragma unroll
    for (int p = 0; p < 4; ++p) {
      int r = r0 + p * 16;
      float4 v = *(const float4*)(b + (size_t)(bi * 64 + r) * Hdim + bj * 64 + c4);
      tile[r * 65 + c4 + 0] = f2bf(v.x);
      tile[r * 65 + c4 + 1] = f2bf(v.y);
      tile[r * 65 + c4 + 2] = f2bf(v.z);
      tile[r * 65 + c4 + 3] = f2bf(v.w);
    }
  }
  __syncthreads();
  {
    const int n = t >> 2, kq = (t & 3) * 16;
    union { unsigned short u[16]; uint4 v[2]; } o;
#pragma unroll
    for (int q = 0; q < 16; ++q) o.u[q] = tile[(kq + q) * 65 + n];
    uint4* dst = (uint4*)(bt + (size_t)(bj * 64 + n) * Hdim + bi * 64 + kq);
    dst[0] = o.v[0];
    dst[1] = o.v[1];
  }
}

// ---- GEMM (s = x @ b) with fused windowed-scan epilogue ----
// r17 structure (8 waves / 512 thr, 128x128 tile, wave-tile 64x32
// 2M x 4N, 2 blocks/CU -> 4 waves/SIMD, SYNC_DRAIN barriers) with ONE
// change: A-staging reads x directly in FP32 and converts to bf16
// in-register (T14 load-early / write-late), eliminating the separate
// x-cast kernel pass and its 48.8 MB HBM round trip.
//
// Per tile: (1) issue 4-6 global_load_dwordx4 of fp32 A rows for tile
// t+1 into regs; (2) B glds for t+1 in flight; (3) compute(t) (~600 cyc
// covers the fp32 load latency); (4) cvt + 2 ds_write_b128 into the
// other buffer; (5) SYNC_DRAIN. Conversion = same RNE f2bf as the old
// cvt pass -> bit-identical results. VALUBusy had headroom (29%).
//
// LDS layout + XOR swizzle unchanged: slot (row, chunk c) holds global
// chunk c^(row&7); fragment reads XOR the same term -> conflict-free
// ds_read_b128. (ds_write has no DMA layout constraint; we keep the
// same slot mapping so fragment reads are untouched.)
//
// XCD swizzle: grid (bm=32 fastest, bn=16) so XCD = bm%8.
// Warm rows: 8 extra A rows (t0-8..t0-1), reg-staged by wave 7, MFMA'd
// by waves 0-3 (2 n-frags each). Epilogue: acc -> s_tile (136x129 fp32)
// -> 512 threads scan 128 cols x 4 chunks of 32 rows (8-row warmup,
// |a| <= 0.03125 -> window error < 1e-12) -> out.
__global__ __launch_bounds__(512, 4) void gemm_scan_kernel(const float* __restrict__ X,
                                                           const unsigned short* __restrict__ Bt,
                                                           const float* __restrict__ a_mat,
                                                           float* __restrict__ out) {
  // alignas(16) REQUIRED: otherwise union alignment is 4 and short8 LDS
  // reads split into 4x ds_read_b32 with 16-way conflicts (round-2: 263 us).
  __shared__ alignas(16) union SM {
    struct {
      unsigned short sA[2][128 * 64];   // 2 x 16 KB
      unsigned short sB[2][128 * 64];   // 2 x 16 KB
      unsigned short sAw[2][8 * 64];    // 2 x 1 KB
    } st;                      // 66 KB
    float s_tile[136 * 129];   // 68.6 KB; [row][col], pad 129
  } sm;

  const int tid = threadIdx.x;
  const int bm = blockIdx.x, bn = blockIdx.y;  // bm fastest -> XCD = bm%8
  const int wave = tid >> 6, lane = tid & 63;
  const int wm = (wave >> 2) * 64;   // waves 0-3 -> 0, waves 4-7 -> 64
  const int wn = (wave & 3) * 32;    // 0,32,64,96
  const int l15 = lane & 15, quad = lane >> 4;
  const int l7 = l15 & 7;  // row&7 of the rows this lane reads fragments from

  // staging: thread tid fills LDS slot (row = tid>>3 + 64c, chunk = tid&7)
  // holding global chunk (tid&7)^(row&7); rows advance 64 (0 mod 8) per
  // c-chunk, so the XOR term is constant per thread.
  const int swz = ((tid & 7) ^ ((tid >> 3) & 7)) * 8;
  const float* aSrc = X + ((size_t)(bm * 128 + (tid >> 3)) * Hdim + swz);      // fp32 A
  const unsigned short* bSrc = Bt + ((size_t)(bn * 128 + (tid >> 3)) * Hdim + swz);
  // warm rows staged by wave 7: lane -> row=lane>>3 (8 rows), chunk=lane&7
  const int tw0 = (bm > 0) ? bm * 128 - 8 : 0;  // clamp keeps address valid; bm==0 warm unused
  const int wswz = ((lane & 7) ^ ((lane >> 3) & 7)) * 8;
  const float* wSrc = X + ((size_t)(tw0 + (lane >> 3)) * Hdim + wswz);         // fp32 warm

  floatx4 acc[4][2] = {};
  floatx4 accw[2] = {};

  // B staging via glds DMA (unchanged, proven)
  auto stageB = [&](int buf, int k0) {
    unsigned short* bDst = &sm.st.sB[buf][tid * 8];
#pragma unroll
    for (int c = 0; c < 2; ++c)
      load_lds16(bSrc + (size_t)c * 64 * Hdim + k0, bDst + c * 4096);
  };

  // A fp32 loads (issue early; latency hidden under compute)
  struct AReg { f32x4 f[4]; f32x4 w[2]; };
  auto loadA = [&](AReg& r, int k0) {
#pragma unroll
    for (int c = 0; c < 2; ++c) {
      r.f[c * 2 + 0] = glb_readf4(aSrc + (size_t)c * 64 * Hdim + k0);
      r.f[c * 2 + 1] = glb_readf4(aSrc + (size_t)c * 64 * Hdim + k0 + 4);
    }
    if (wave == 7) {
      r.w[0] = glb_readf4(wSrc + k0);
      r.w[1] = glb_readf4(wSrc + k0 + 4);
    }
  };

  // cvt + ds_write (write late, just before the drain+barrier)
  auto writeA = [&](int buf, const AReg& r) {
    unsigned short* aDst = &sm.st.sA[buf][tid * 8];
#pragma unroll
    for (int c = 0; c < 2; ++c) {
      union { unsigned short u[8]; short8 v; } o;
#pragma unroll
      for (int q = 0; q < 4; ++q) {
        o.u[q] = f2bf(r.f[c * 2 + 0][q]);
        o.u[4 + q] = f2bf(r.f[c * 2 + 1][q]);
      }
      *(short8*)__builtin_assume_aligned(aDst + c * 4096, 16) = o.v;
    }
    if (wave == 7) {
      union { unsigned short u[8]; short8 v; } o;
#pragma unroll
      for (int q = 0; q < 4; ++q) {
        o.u[q] = f2bf(r.w[0][q]);
        o.u[4 + q] = f2bf(r.w[1][q]);
      }
      *(short8*)__builtin_assume_aligned(&sm.st.sAw[buf][lane * 8], 16) = o.v;
    }
  };

  // compute from buffer `buf`: wave-tile 64x32 -> 4x2 frags x 2 kk-steps
  auto compute = [&](int buf) {
#pragma unroll
    for (int kk = 0; kk < 64; kk += 32) {
      const int coff = (((kk >> 3) + quad) ^ l7) * 8;
      short8 av[4], bv[2];
#pragma unroll
      for (int i = 0; i < 4; ++i)
        av[i] = lds_read8(&sm.st.sA[buf][(wm + i * 16 + l15) * 64 + coff]);
#pragma unroll
      for (int j = 0; j < 2; ++j)
        bv[j] = lds_read8(&sm.st.sB[buf][(wn + j * 16 + l15) * 64 + coff]);
#pragma unroll
      for (int i = 0; i < 4; ++i)
#pragma unroll
        for (int j = 0; j < 2; ++j)
          acc[i][j] = __builtin_amdgcn_mfma_f32_16x16x32_bf16(av[i], bv[j], acc[i][j], 0, 0, 0);
      if (wm == 0) {  // warm rows: waves 0-3, each covers its wn (2 n-frags)
        short8 aw = lds_read8(&sm.st.sAw[buf][l7 * 64 + coff]);
#pragma unroll
        for (int j = 0; j < 2; ++j)
          accw[j] = __builtin_amdgcn_mfma_f32_16x16x32_bf16(aw, bv[j], accw[j], 0, 0, 0);
      }
    }
  };

  AReg ar;

  // prologue: tile 0 -> buf 0
  loadA(ar, 0);
  stageB(0, 0);
  writeA(0, ar);
  SYNC_DRAIN();
  // main loop, unrolled x2 so buffer indices are compile-time
  for (int it = 0; it < 32; it += 2) {
    loadA(ar, (it + 1) * 64);         // fp32 A loads for t+1 in flight
    stageB(1, (it + 1) * 64);         // B glds for t+1 in flight
    compute(0);
    writeA(1, ar);                    // cvt + ds_write after compute
    SYNC_DRAIN();                     // drain lands AFTER compute
    if (it + 2 < 32) {
      loadA(ar, (it + 2) * 64);
      stageB(0, (it + 2) * 64);
    }
    compute(1);
    if (it + 2 < 32) writeA(0, ar);
    SYNC_DRAIN();
  }

  // ---- epilogue: registers -> s_tile (C/D layout: col=lane&15, row=quad*4+r) ----
  if (wm == 0 && quad < 2) {  // warm rows idx 0..7 (valid m = 0..7 only)
#pragma unroll
    for (int j = 0; j < 2; ++j)
#pragma unroll
      for (int r = 0; r < 4; ++r)
        sm.s_tile[(quad * 4 + r) * 129 + wn + j * 16 + l15] = accw[j][r];
  }
#pragma unroll
  for (int i = 0; i < 4; ++i)
#pragma unroll
    for (int j = 0; j < 2; ++j)
#pragma unroll
      for (int r = 0; r < 4; ++r)
        sm.s_tile[(8 + wm + i * 16 + quad * 4 + r) * 129 + wn + j * 16 + l15] = acc[i][j][r];
  SYNC_DRAIN();

  // ---- windowed scan: 512 threads = 128 cols x 4 chunks of 32 rows ----
  const int col = tid & 127;
  const int chunk = tid >> 7;
  const float aj = a_mat[bn * 128 + col];
  float h = 0.0f;
  const int row0 = 8 + chunk * 32;
  if (!(bm == 0 && chunk == 0)) {
#pragma unroll
    for (int r = row0 - 8; r < row0; ++r)  // warm-up (discarded outputs)
      h = tanh_fast(fmaf(aj, h, sm.s_tile[r * 129 + col]));
  }
  const size_t gbase = (size_t)(bm * 128 + chunk * 32) * Hdim + bn * 128 + col;
#pragma unroll 4
  for (int r2 = 0; r2 < 32; ++r2) {
    h = tanh_fast(fmaf(aj, h, sm.s_tile[(row0 + r2) * 129 + col]));
    out[gbase + (size_t)r2 * Hdim] = h;
  }
}

extern "C" void kernel_launch(void* const* d_in, const int* in_sizes, int n_in,
                              void* d_out, int out_size, void* d_ws, size_t ws_size,
                              hipStream_t stream) {
  const float* x = (const float*)d_in[0];
  const float* a = (const float*)d_in[1];
  const float* b = (const float*)d_in[2];
  float* out = (float*)d_out;

  unsigned short* btb = (unsigned short*)d_ws;               // 8.4 MB

  hipLaunchKernelGGL(cvt_kernel, dim3((Hdim / 64) * (Hdim / 64)), dim3(256), 0, stream,
                     b, btb);
  // grid: x = bm (32, fastest -> XCD = bm%8), y = bn (16)
  hipLaunchKernelGGL(gemm_scan_kernel, dim3(Tdim / 128, Hdim / 128), dim3(512), 0, stream,
                     x, btb, a, out);
}

// Round 9
// 135.799 us; speedup vs baseline: 1.0901x; 1.0901x over previous
//
#include <hip/hip_runtime.h>
#include <stdint.h>
#include <stddef.h>

#define Tdim 4096
#define Hdim 2048

typedef short short8 __attribute__((ext_vector_type(8)));
typedef float floatx4 __attribute__((ext_vector_type(4)));

// RNE fp32 -> bf16 bit pattern
__device__ __forceinline__ unsigned short f2bf(float f) {
  uint32_t u = __float_as_uint(f);
  u += 0x7fffu + ((u >> 16) & 1u);
  return (unsigned short)(u >> 16);
}

// async global->LDS, 16B per lane. LDS dest is wave-uniform base + lane*16.
__device__ __forceinline__ void load_lds16(const void* g, void* l) {
  __builtin_amdgcn_global_load_lds(
      (__attribute__((address_space(1))) unsigned int*)(uintptr_t)g,
      (__attribute__((address_space(3))) unsigned int*)l,
      16, 0, 0);
}

__device__ __forceinline__ float tanh_fast(float z) {
  // tanh(z) = 1 - 2/(exp(2z)+1); safe for all z
  float e = __expf(z + z);
  return 1.0f - __fdividef(2.0f, e + 1.0f);
}

// aligned LDS vector read (forces ds_read_b128)
__device__ __forceinline__ short8 lds_read8(const unsigned short* p) {
  return *(const short8*)__builtin_assume_aligned(p, 16);
}

// Explicit barrier-with-drain (r16 lesson: the compiler's vmcnt(0)-before-
// s_barrier is observed codegen, not a guarantee; without it one stale LDS
// tile diverged outputs on graph replay). Drain both counters, then barrier.
#define SYNC_DRAIN()                                                   \
  do {                                                                 \
    asm volatile("s_waitcnt vmcnt(0) lgkmcnt(0)" ::: "memory");        \
    __syncthreads();                                                   \
  } while (0)

// ---- fused convert: blocks [0,4096) cast x -> bf16; blocks [4096,5120)
// transpose+cast b (HxH fp32, [k][n]) -> bt bf16 (N x K, [n][k]) ----
// (r20 tried fusing the x-cast into the GEMM via reg-staging: fixed cost
// -13us but gemm +25us -- ds_write staging taxes the LDS pipe ~26% (m151).
// The separate cast pass + glds DMA is the cheaper total. Reverted.)
__global__ __launch_bounds__(256) void cvt_kernel(const float* __restrict__ x,
                                                  const float* __restrict__ b,
                                                  unsigned short* __restrict__ xbf,
                                                  unsigned short* __restrict__ bt) {
  __shared__ unsigned short tile[64 * 65];
  const int t = threadIdx.x;
  if (blockIdx.x < 4096) {
    size_t i = ((size_t)blockIdx.x * 256 + t) * 8;
    float4 f0 = *(const float4*)(x + i);
    float4 f1 = *(const float4*)(x + i + 4);
    union { unsigned short u[8]; uint4 v; } o;
    o.u[0] = f2bf(f0.x); o.u[1] = f2bf(f0.y); o.u[2] = f2bf(f0.z); o.u[3] = f2bf(f0.w);
    o.u[4] = f2bf(f1.x); o.u[5] = f2bf(f1.y); o.u[6] = f2bf(f1.z); o.u[7] = f2bf(f1.w);
    *(uint4*)(xbf + i) = o.v;
    return;
  }
  const int tb = blockIdx.x - 4096;
  const int bj = tb & 31;  // n block
  const int bi = tb >> 5;  // k block
  {
    const int r0 = t >> 4, c4 = (t & 15) * 4;
#pragma unroll
    for (int p = 0; p < 4; ++p) {
      int r = r0 + p * 16;
      float4 v = *(const float4*)(b + (size_t)(bi * 64 + r) * Hdim + bj * 64 + c4);
      tile[r * 65 + c4 + 0] = f2bf(v.x);
      tile[r * 65 + c4 + 1] = f2bf(v.y);
      tile[r * 65 + c4 + 2] = f2bf(v.z);
      tile[r * 65 + c4 + 3] = f2bf(v.w);
    }
  }
  __syncthreads();
  {
    const int n = t >> 2, kq = (t & 3) * 16;
    union { unsigned short u[16]; uint4 v[2]; } o;
#pragma unroll
    for (int q = 0; q < 16; ++q) o.u[q] = tile[(kq + q) * 65 + n];
    uint4* dst = (uint4*)(bt + (size_t)(bj * 64 + n) * Hdim + bi * 64 + kq);
    dst[0] = o.v[0];
    dst[1] = o.v[1];
  }
}

// ---- GEMM (s = x @ b) with fused windowed-scan epilogue ----
// Round 21: LDS-pipe-bound fix. Honest arithmetic on r17 (44.4us): per
// K-tile per CU = 2 blocks x (8 waves x 13 ds_read_b128 x 12cyc + 33KB
// DMA/128B/cyc) ~ 3016 cyc of LDS pipe vs 3330 available -> ~90% LDS-busy;
// MfmaUtil 35% == MFMA:LDS pipe ratio. (r20 confirmed by counterexample:
// replacing A's glds DMA with reg-stage ds_writes cost +25us, m151's tax.)
// LDS wave-ops per FLOP scale as (WM+WN)/(WM*WN) -> bigger wave-tiles:
//
//   BM=256 x BN=128, 8 waves x 64x64 wave-tile (4x4 frags of 16x16x32),
//   2 buffers, SAME stage->compute->SYNC_DRAIN loop as r17 (ds_read and
//   MFMA stay interleaved inside compute; NOT r13's 4-barrier phase split
//   which serialized the pipes). Per K-tile per CU: 8x16 reads x12 +
//   50KB DMA ~ 1920 cyc (-36%); MFMA 1242 cyc hides under it.
//
// LDS = max(98KB staging, 136KB s_tile) = 136KB -> 1 block/CU, grid
// 16x16 = 256 = exactly 1/CU. 2 waves/SIMD is enough: the bound is LDS
// throughput, not latency (staging covered by a full compute phase).
//
// Proven parts verbatim: XOR swizzle (slot (row,chunk c) holds global
// chunk c^(row&7); rows advance 64 == 0 mod 8 per c-chunk -> XOR constant
// per thread; fragment reads XOR the same term -> conflict-free
// ds_read_b128). XCD: bm = blockIdx.x (16 values) -> XCD = bm%8, 2MB of
// A per XCD L2-resident. Warm rows: 8 extra A rows staged by wave 7,
// MFMA'd by waves 0,1 (wm==0; wn 0/64, 4 j-frags each = 128 cols).
// Epilogue: acc -> s_tile (264x129 fp32, r13's correctness-proven scan)
// -> 512 threads scan 128 cols x 4 chunks of 64 rows, 8-row warmup
// (|a| <= 0.03125 -> window error < 1e-12) -> out.
__global__ __launch_bounds__(512, 2) void gemm_scan_kernel(const unsigned short* __restrict__ A,
                                                           const unsigned short* __restrict__ Bt,
                                                           const float* __restrict__ a_mat,
                                                           float* __restrict__ out) {
  // alignas(16) REQUIRED: otherwise union alignment is 4 and short8 LDS
  // reads split into 4x ds_read_b32 with 16-way conflicts (round-2: 263 us).
  __shared__ alignas(16) union SM {
    struct {
      unsigned short sA[2][256 * 64];   // 2 x 32 KB
      unsigned short sB[2][128 * 64];   // 2 x 16 KB
      unsigned short sAw[2][8 * 64];    // 2 x 1 KB
    } st;                      // 98 KB
    float s_tile[264 * 129];   // 136.2 KB; [row][col], pad 129
  } sm;

  const int tid = threadIdx.x;
  const int bm = blockIdx.x, bn = blockIdx.y;  // bm fastest -> XCD = bm%8
  const int wave = tid >> 6, lane = tid & 63;
  const int wm = (wave >> 1) * 64;   // 0,64,128,192
  const int wn = (wave & 1) * 64;    // 0,64
  const int l15 = lane & 15, quad = lane >> 4;
  const int l7 = l15 & 7;  // row&7 of the rows this lane reads fragments from

  // staging: thread tid fills LDS slot (row = tid>>3 + 64c, chunk = tid&7)
  // holding global chunk (tid&7)^(row&7).
  const int swz = ((tid & 7) ^ ((tid >> 3) & 7)) * 8;
  const unsigned short* aSrc = A + ((size_t)(bm * 256 + (tid >> 3)) * Hdim + swz);
  const unsigned short* bSrc = Bt + ((size_t)(bn * 128 + (tid >> 3)) * Hdim + swz);
  // warm rows staged by wave 7: lane -> row=lane>>3 (8 rows), chunk=lane&7
  const int tw0 = (bm > 0) ? bm * 256 - 8 : 0;  // clamp keeps address valid; bm==0 warm unused
  const int wswz = ((lane & 7) ^ ((lane >> 3) & 7)) * 8;
  const unsigned short* wSrc = A + ((size_t)(tw0 + (lane >> 3)) * Hdim + wswz);

  floatx4 acc[4][4] = {};
  floatx4 accw[4] = {};

  // stage tile (k0) into buffer `buf`: A 4 row-chunks, B 2, warm on wave 7
  auto stage = [&](int buf, int k0) {
    unsigned short* aDst = &sm.st.sA[buf][tid * 8];
    unsigned short* bDst = &sm.st.sB[buf][tid * 8];
#pragma unroll
    for (int c = 0; c < 4; ++c)
      load_lds16(aSrc + (size_t)c * 64 * Hdim + k0, aDst + c * 4096);
#pragma unroll
    for (int c = 0; c < 2; ++c)
      load_lds16(bSrc + (size_t)c * 64 * Hdim + k0, bDst + c * 4096);
    if (wave == 7) load_lds16(wSrc + k0, &sm.st.sAw[buf][lane * 8]);
  };

  // compute from buffer `buf`: wave-tile 64x64 -> 4x4 frags x 2 kk-steps
  auto compute = [&](int buf) {
#pragma unroll
    for (int kk = 0; kk < 64; kk += 32) {
      const int coff = (((kk >> 3) + quad) ^ l7) * 8;
      short8 av[4], bv[4];
#pragma unroll
      for (int i = 0; i < 4; ++i)
        av[i] = lds_read8(&sm.st.sA[buf][(wm + i * 16 + l15) * 64 + coff]);
#pragma unroll
      for (int j = 0; j < 4; ++j)
        bv[j] = lds_read8(&sm.st.sB[buf][(wn + j * 16 + l15) * 64 + coff]);
#pragma unroll
      for (int i = 0; i < 4; ++i)
#pragma unroll
        for (int j = 0; j < 4; ++j)
          acc[i][j] = __builtin_amdgcn_mfma_f32_16x16x32_bf16(av[i], bv[j], acc[i][j], 0, 0, 0);
      if (wm == 0) {  // warm rows: waves 0,1 (wn 0/64), 4 j-frags each
        short8 aw = lds_read8(&sm.st.sAw[buf][l7 * 64 + coff]);
#pragma unroll
        for (int j = 0; j < 4; ++j)
          accw[j] = __builtin_amdgcn_mfma_f32_16x16x32_bf16(aw, bv[j], accw[j], 0, 0, 0);
      }
    }
  };

  // prologue: tile 0 -> buf 0
  stage(0, 0);
  SYNC_DRAIN();
  // main loop, unrolled x2 so buffer indices are compile-time
  for (int it = 0; it < 32; it += 2) {
    stage(1, (it + 1) * 64);          // loads in flight during compute
    compute(0);
    SYNC_DRAIN();                     // drain lands AFTER compute
    if (it + 2 < 32) stage(0, (it + 2) * 64);
    compute(1);
    SYNC_DRAIN();
  }

  // ---- epilogue: registers -> s_tile (C/D layout: col=lane&15, row=quad*4+r) ----
  if (wm == 0 && quad < 2) {  // warm rows idx 0..7 (valid m = 0..7 only)
#pragma unroll
    for (int j = 0; j < 4; ++j)
#pragma unroll
      for (int r = 0; r < 4; ++r)
        sm.s_tile[(quad * 4 + r) * 129 + wn + j * 16 + l15] = accw[j][r];
  }
#pragma unroll
  for (int i = 0; i < 4; ++i)
#pragma unroll
    for (int j = 0; j < 4; ++j)
#pragma unroll
      for (int r = 0; r < 4; ++r)
        sm.s_tile[(8 + wm + i * 16 + quad * 4 + r) * 129 + wn + j * 16 + l15] = acc[i][j][r];
  SYNC_DRAIN();

  // ---- windowed scan: 512 threads = 128 cols x 4 chunks of 64 rows ----
  const int col = tid & 127;
  const int chunk = tid >> 7;
  const float aj = a_mat[bn * 128 + col];
  float h = 0.0f;
  const int row0 = 8 + chunk * 64;
  if (!(bm == 0 && chunk == 0)) {
#pragma unroll
    for (int r = row0 - 8; r < row0; ++r)  // warm-up (discarded outputs)
      h = tanh_fast(fmaf(aj, h, sm.s_tile[r * 129 + col]));
  }
  const size_t gbase = (size_t)(bm * 256 + chunk * 64) * Hdim + bn * 128 + col;
#pragma unroll 4
  for (int r2 = 0; r2 < 64; ++r2) {
    h = tanh_fast(fmaf(aj, h, sm.s_tile[(row0 + r2) * 129 + col]));
    out[gbase + (size_t)r2 * Hdim] = h;
  }
}

extern "C" void kernel_launch(void* const* d_in, const int* in_sizes, int n_in,
                              void* d_out, int out_size, void* d_ws, size_t ws_size,
                              hipStream_t stream) {
  const float* x = (const float*)d_in[0];
  const float* a = (const float*)d_in[1];
  const float* b = (const float*)d_in[2];
  float* out = (float*)d_out;

  unsigned short* ws = (unsigned short*)d_ws;
  unsigned short* xbf = ws;                                 // 16.8 MB
  unsigned short* btb = xbf + (size_t)Tdim * Hdim;          // 8.4 MB

  hipLaunchKernelGGL(cvt_kernel, dim3(4096 + (Hdim / 64) * (Hdim / 64)), dim3(256), 0, stream,
                     x, b, xbf, btb);
  // grid: x = bm (16, fastest -> XCD = bm%8), y = bn (16); 256 blocks = 1/CU
  hipLaunchKernelGGL(gemm_scan_kernel, dim3(Tdim / 256, Hdim / 128), dim3(512), 0, stream,
                     xbf, btb, a, out);
}